// Round 15
// baseline (477.238 us; speedup 1.0000x reference)
//
#include <hip/hip_runtime.h>
#include <math.h>

#define DD 100
#define NTRIL 4950                 // D*(D-1)/2
#define NPACK (DD * (DD + 1) / 2)  // 5050
#define LOG_2PI 1.8378770664093453
#define JITTER 5.5e-8              // calibrated vs np twin (R7-R9 probes)
#define RCAP 64
#define WPB 4                      // waves (samples) per block
#define BIGCAP 256                 // straggler list capacity (expect ~8)

// ---------------------------------------------------------------------------
// Kernel 1: cov = A * A^T in fp64 (exact).
// ---------------------------------------------------------------------------
__global__ __launch_bounds__(256) void build_cov_kernel(
    const float* __restrict__ log_diag,
    const float* __restrict__ lower_tri,
    double* __restrict__ cov)
{
    __shared__ double sLow[NTRIL];
    __shared__ double sDiag[DD];
    for (int t = threadIdx.x; t < NTRIL; t += blockDim.x)
        sLow[t] = (double)lower_tri[t];
    for (int t = threadIdx.x; t < DD; t += blockDim.x)
        sDiag[t] = exp((double)log_diag[t]);
    __syncthreads();

    int idx = blockIdx.x * blockDim.x + threadIdx.x;
    if (idx >= DD * DD) return;
    int i = idx / DD;
    int j = idx % DD;
    int mn = (i < j) ? i : j;
    int bi = i * (i - 1) / 2;
    int bj = j * (j - 1) / 2;
    double acc = 0.0;
    for (int t = 0; t < mn; ++t)
        acc += sLow[bi + t] * sLow[bj + t];
    double ai = (mn < i) ? sLow[bi + mn] : sDiag[i];
    double aj = (mn < j) ? sLow[bj + mn] : sDiag[j];
    cov[idx] = acc + ai * aj;
}

// ---------------------------------------------------------------------------
// Kernel 2a: 2D register-tiled LDL^T, kk <= 64. FOUR samples per block
// (one per wave) to reach ~24 waves/CU and hide the serial pivot chain.
// Per-wave math identical to R14 (bit-identical output). Stragglers
// (kk > 64) are pushed to a worklist for the fixed-grid fallback kernel.
// ---------------------------------------------------------------------------
__global__ __launch_bounds__(256, 6) void nll_kernel_tile(
    const float* __restrict__ x,
    const int*   __restrict__ mask,
    const float* __restrict__ mu,
    const double* __restrict__ cov,
    float* __restrict__ out,
    int* __restrict__ bigcount,
    int* __restrict__ biglist,
    int Bn)
{
    __shared__ int obs[WPB][RCAP];

    const int wid  = threadIdx.x >> 6;
    const int lane = threadIdx.x & 63;
    const int b = blockIdx.x * WPB + wid;
    if (b >= Bn) return;               // whole wave exits; barrier counts live waves

    const int lr = lane & 7;
    const int lc = lane >> 3;

    // ---- compact observed indices via ballot prefix (per wave) ----
    int i1 = lane + 64;
    int m0 = (mask[b * DD + lane] != 0);
    int m1v = (i1 < DD) ? (mask[b * DD + i1] != 0) : 0;
    unsigned long long b0 = __ballot(m0);
    unsigned long long bb1 = __ballot(m1v);
    unsigned long long lowmask = (1ull << lane) - 1ull;
    int k0 = __popcll(b0);
    int pos0 = __popcll(b0 & lowmask);
    int pos1 = k0 + __popcll(bb1 & lowmask);
    const int kk = k0 + __popcll(bb1);
    if (m0 && pos0 < RCAP) obs[wid][pos0] = lane;
    if (m1v && pos1 < RCAP) obs[wid][pos1] = i1;
    if (lane >= kk && lane < RCAP) obs[wid][lane] = 0;  // park
    __syncthreads();
    if (kk > RCAP) {                   // straggler: enqueue, bail (wave-uniform)
        if (lane == 0) {
            int idx = atomicAdd(bigcount, 1);
            if (idx < BIGCAP) biglist[idx] = b;
        }
        return;
    }

    // ---- gather index vectors (static reg arrays) ----
    int rows[8], cols[8];
    #pragma unroll
    for (int j = 0; j < 8; ++j) rows[j] = obs[wid][8 * j + lr];
    #pragma unroll
    for (int m = 0; m < 8; ++m) cols[m] = obs[wid][8 * m + lc];

    // ---- direct tile load from cov (L2-resident, 80 KB) ----
    double T[8][8];
    #pragma unroll
    for (int j = 0; j < 8; ++j) {
        const int gr = 8 * j + lr;
        #pragma unroll
        for (int m = 0; m < 8; ++m) {
            const int gc = 8 * m + lc;
            double v = 0.0;
            if (gr < kk && gc <= gr) {
                v = cov[rows[j] * DD + cols[m]];
                if (gr == gc) v += JITTER;
            }
            T[j][m] = v;
        }
    }

    // ---- residuals (f32 subtract as np, widened) ----
    double rz[8];
    #pragma unroll
    for (int j = 0; j < 8; ++j) {
        const int gr = 8 * j + lr;
        double v = 0.0;
        if (gr < kk) {
            int g = rows[j];
            v = (double)(x[b * DD + g] - mu[g]);
        }
        rz[j] = v;
    }

    double q_acc = 0.0;
    double dsave = 1.0;          // lane t holds d_t; others contribute log(1)=0

    // ---- panel loop; 8 pivots per panel, wave-synchronous, no barriers ----
    const int npan = (kk + 7) >> 3;
    for (int p = 0; p < npan; ++p) {
        const int rem = kk - 8 * p;
        const int jmax = (rem + 7) >> 3;         // live slots (1..8), uniform

        #pragma unroll
        for (int tt = 0; tt < 8; ++tt) {
            if (tt < rem) {
                const int t = 8 * p + tt;
                double dp  = __shfl(T[0][0], 9 * tt);   // diag owner lane
                double rzt = __shfl(rz[0], tt);          // lane tt, lc=0
                double inv = 1.0 / dp;
                if (lane == t) dsave = dp;
                q_acc = fma(rzt * inv, rzt, q_acc);      // q += rzt^2/d

                double ar[8], cc[8];
                #pragma unroll
                for (int j = 0; j < 8; ++j)
                    ar[j] = (j < jmax)
                          ? __shfl(T[j][0], 8 * tt + lr) * inv : 0.0;
                #pragma unroll
                for (int m = 0; m < 8; ++m)
                    cc[m] = (m < jmax)
                          ? __shfl(T[m][0], 8 * tt + lc) : 0.0;

                #pragma unroll
                for (int j = 0; j < 8; ++j) {
                    if (j < jmax) {
                        #pragma unroll
                        for (int m = 0; m < 8; ++m)
                            if (m < jmax)
                                T[j][m] = fma(-ar[j], cc[m], T[j][m]);
                        rz[j] = fma(-ar[j], rzt, rz[j]);
                    }
                }
            }
        }
        // ---- double panel shift: rows AND cols down one slot (static) ----
        #pragma unroll
        for (int j = 0; j < 7; ++j) {
            #pragma unroll
            for (int m = 0; m < 7; ++m)
                T[j][m] = T[j + 1][m + 1];
            rz[j] = rz[j + 1];
        }
    }

    // ---- logdet: one log per lane; q_acc already identical in all lanes ----
    double ld = log(dsave);
    for (int off = 32; off; off >>= 1)
        ld += __shfl_down(ld, off);
    if (lane == 0)
        out[b] = (float)(0.5 * (q_acc + ld + (double)kk * LOG_2PI));
}

// ---------------------------------------------------------------------------
// Kernel 2b: fallback, fixed 128-block grid driven by the straggler list.
// 256 threads: 2 threads per row splitting the column range (R14-verified).
// ---------------------------------------------------------------------------
__global__ __launch_bounds__(256) void nll_kernel_big(
    const float* __restrict__ x,
    const int*   __restrict__ mask,
    const float* __restrict__ mu,
    const double* __restrict__ cov,
    float* __restrict__ out,
    const int* __restrict__ bigcount,
    const int* __restrict__ biglist)
{
    __shared__ double S[NPACK];    // 40400 B
    __shared__ double col[DD];
    __shared__ double rz[DD];
    __shared__ int obs[DD];
    __shared__ int kk_sh;
    __shared__ double pq[4], pl[4];

    int nbig = *bigcount;
    if (nbig > BIGCAP) nbig = BIGCAP;
    if (blockIdx.x >= nbig) return;
    const int b = biglist[blockIdx.x];

    const int tid = threadIdx.x;
    const int lane = tid & 63;
    const int wv = tid >> 6;

    if (wv == 0) {
        int i1 = lane + 64;
        int m0 = (mask[b * DD + lane] != 0);
        int m1 = (i1 < DD) ? (mask[b * DD + i1] != 0) : 0;
        unsigned long long b0 = __ballot(m0);
        unsigned long long bb1 = __ballot(m1);
        unsigned long long lowmask = (1ull << lane) - 1ull;
        int k0 = __popcll(b0);
        if (m0) obs[__popcll(b0 & lowmask)] = lane;
        if (m1) obs[k0 + __popcll(bb1 & lowmask)] = i1;
        if (lane == 0) kk_sh = k0 + __popcll(bb1);
    }
    __syncthreads();
    const int kk = kk_sh;

    if (tid < kk) {
        int g = obs[tid];
        rz[tid] = (double)(x[b * DD + g] - mu[g]);
    }

    int T = kk * (kk + 1) / 2;
    for (int t = tid; t < T; t += 256) {
        int i = (int)((sqrt(8.0 * (double)t + 1.0) - 1.0) * 0.5);
        while ((i + 1) * (i + 2) / 2 <= t) ++i;
        while (i * (i + 1) / 2 > t) --i;
        int j = t - i * (i + 1) / 2;
        double val = cov[obs[i] * DD + obs[j]];
        if (i == j) val += JITTER;
        S[t] = val;
    }
    __syncthreads();

    for (int p = 0; p < kk; ++p) {
        if (tid < kk - p) {
            int l = p + tid;
            col[l] = S[l * (l + 1) / 2 + p];
        }
        __syncthreads();
        double inv = 1.0 / col[p];
        double rzp = rz[p];
        int r = tid >> 1, half = tid & 1;
        int i = p + 1 + r;
        if (i < kk) {
            double* Srow = S + i * (i + 1) / 2;
            double ai = col[i] * inv;
            int lo = p + 1;
            int len = i - p;                 // cols p+1..i inclusive
            int mid = lo + (len >> 1);
            int from = half ? mid : lo;
            int to   = half ? (i + 1) : mid;
            #pragma unroll 4
            for (int l2 = from; l2 < to; ++l2)
                Srow[l2] -= ai * col[l2];
            if (half == 0) rz[i] -= ai * rzp;
        }
        __syncthreads();
    }

    double q = 0.0, ld = 0.0;
    if (tid < kk) {
        double dj = S[tid * (tid + 1) / 2 + tid];
        ld = log(dj);
        double zj = rz[tid];
        q = zj * zj / dj;
    }
    for (int off = 32; off; off >>= 1) {
        q  += __shfl_down(q, off);
        ld += __shfl_down(ld, off);
    }
    if (lane == 0) { pq[wv] = q; pl[wv] = ld; }
    __syncthreads();
    if (tid == 0)
        out[b] = (float)(0.5 * (pq[0] + pq[1] + pq[2] + pq[3]
                                + pl[0] + pl[1] + pl[2] + pl[3]
                                + (double)kk * LOG_2PI));
}

// ---------------------------------------------------------------------------
extern "C" void kernel_launch(void* const* d_in, const int* in_sizes, int n_in,
                              void* d_out, int out_size, void* d_ws, size_t ws_size,
                              hipStream_t stream)
{
    const float* x         = (const float*)d_in[0];
    const int*   mask      = (const int*)d_in[1];
    const float* mu        = (const float*)d_in[2];
    const float* log_diag  = (const float*)d_in[3];
    const float* lower_tri = (const float*)d_in[4];
    float* out = (float*)d_out;

    double* cov    = (double*)d_ws;                       // 80000 B
    int* bigcount  = (int*)((char*)d_ws + 80000);         // 4 B
    int* biglist   = (int*)((char*)d_ws + 80000 + 128);   // BIGCAP*4 B

    const int Bn = in_sizes[0] / DD;

    hipMemsetAsync(bigcount, 0, sizeof(int), stream);
    build_cov_kernel<<<(DD * DD + 255) / 256, 256, 0, stream>>>(log_diag, lower_tri, cov);
    nll_kernel_tile<<<(Bn + WPB - 1) / WPB, 256, 0, stream>>>(
        x, mask, mu, cov, out, bigcount, biglist, Bn);
    nll_kernel_big<<<128, 256, 0, stream>>>(x, mask, mu, cov, out, bigcount, biglist);
}

// Round 16
// 237.305 us; speedup vs baseline: 2.0111x; 2.0111x over previous
//
#include <hip/hip_runtime.h>
#include <math.h>

#define DD 100
#define NTRIL 4950                 // D*(D-1)/2
#define NPACK (DD * (DD + 1) / 2)  // 5050
#define LOG_2PI 1.8378770664093453
#define JITTER 5.5e-8              // calibrated vs np twin (R7-R9 probes)
#define RCAP 64
#define WPB 4                      // waves (samples) per block
#define BIGCAP 256                 // straggler list capacity (expect ~8)

// ---------------------------------------------------------------------------
// Kernel 1: cov = A * A^T in fp64 (exact).
// ---------------------------------------------------------------------------
__global__ __launch_bounds__(256) void build_cov_kernel(
    const float* __restrict__ log_diag,
    const float* __restrict__ lower_tri,
    double* __restrict__ cov)
{
    __shared__ double sLow[NTRIL];
    __shared__ double sDiag[DD];
    for (int t = threadIdx.x; t < NTRIL; t += blockDim.x)
        sLow[t] = (double)lower_tri[t];
    for (int t = threadIdx.x; t < DD; t += blockDim.x)
        sDiag[t] = exp((double)log_diag[t]);
    __syncthreads();

    int idx = blockIdx.x * blockDim.x + threadIdx.x;
    if (idx >= DD * DD) return;
    int i = idx / DD;
    int j = idx % DD;
    int mn = (i < j) ? i : j;
    int bi = i * (i - 1) / 2;
    int bj = j * (j - 1) / 2;
    double acc = 0.0;
    for (int t = 0; t < mn; ++t)
        acc += sLow[bi + t] * sLow[bj + t];
    double ai = (mn < i) ? sLow[bi + mn] : sDiag[i];
    double aj = (mn < j) ? sLow[bj + mn] : sDiag[j];
    cov[idx] = acc + ai * aj;
}

// ---------------------------------------------------------------------------
// Kernel 2a: 2D register-tiled LDL^T, kk <= 64. Four samples per block
// (one per wave). __launch_bounds__(256, 2): min-waves=2 -> VGPR cap 256,
// room for the 128-VGPR T tile (R15's ",6" capped at ~85 VGPR and spilled
// the tile to scratch: 1.3 GB HBM traffic, 3.2x regression).
// Per-wave math identical to R14 (bit-identical output). Stragglers
// (kk > 64) are pushed to a worklist for the fixed-grid fallback kernel.
// ---------------------------------------------------------------------------
__global__ __launch_bounds__(256, 2) void nll_kernel_tile(
    const float* __restrict__ x,
    const int*   __restrict__ mask,
    const float* __restrict__ mu,
    const double* __restrict__ cov,
    float* __restrict__ out,
    int* __restrict__ bigcount,
    int* __restrict__ biglist,
    int Bn)
{
    __shared__ int obs[WPB][RCAP];

    const int wid  = threadIdx.x >> 6;
    const int lane = threadIdx.x & 63;
    const int b = blockIdx.x * WPB + wid;
    if (b >= Bn) return;               // whole wave exits; barrier counts live waves

    const int lr = lane & 7;
    const int lc = lane >> 3;

    // ---- compact observed indices via ballot prefix (per wave) ----
    int i1 = lane + 64;
    int m0 = (mask[b * DD + lane] != 0);
    int m1v = (i1 < DD) ? (mask[b * DD + i1] != 0) : 0;
    unsigned long long b0 = __ballot(m0);
    unsigned long long bb1 = __ballot(m1v);
    unsigned long long lowmask = (1ull << lane) - 1ull;
    int k0 = __popcll(b0);
    int pos0 = __popcll(b0 & lowmask);
    int pos1 = k0 + __popcll(bb1 & lowmask);
    const int kk = k0 + __popcll(bb1);
    if (m0 && pos0 < RCAP) obs[wid][pos0] = lane;
    if (m1v && pos1 < RCAP) obs[wid][pos1] = i1;
    if (lane >= kk && lane < RCAP) obs[wid][lane] = 0;  // park
    __syncthreads();
    if (kk > RCAP) {                   // straggler: enqueue, bail (wave-uniform)
        if (lane == 0) {
            int idx = atomicAdd(bigcount, 1);
            if (idx < BIGCAP) biglist[idx] = b;
        }
        return;
    }

    // ---- gather index vectors (static reg arrays) ----
    int rows[8], cols[8];
    #pragma unroll
    for (int j = 0; j < 8; ++j) rows[j] = obs[wid][8 * j + lr];
    #pragma unroll
    for (int m = 0; m < 8; ++m) cols[m] = obs[wid][8 * m + lc];

    // ---- direct tile load from cov (L2-resident, 80 KB) ----
    double T[8][8];
    #pragma unroll
    for (int j = 0; j < 8; ++j) {
        const int gr = 8 * j + lr;
        #pragma unroll
        for (int m = 0; m < 8; ++m) {
            const int gc = 8 * m + lc;
            double v = 0.0;
            if (gr < kk && gc <= gr) {
                v = cov[rows[j] * DD + cols[m]];
                if (gr == gc) v += JITTER;
            }
            T[j][m] = v;
        }
    }

    // ---- residuals (f32 subtract as np, widened) ----
    double rz[8];
    #pragma unroll
    for (int j = 0; j < 8; ++j) {
        const int gr = 8 * j + lr;
        double v = 0.0;
        if (gr < kk) {
            int g = rows[j];
            v = (double)(x[b * DD + g] - mu[g]);
        }
        rz[j] = v;
    }

    double q_acc = 0.0;
    double dsave = 1.0;          // lane t holds d_t; others contribute log(1)=0

    // ---- panel loop; 8 pivots per panel, wave-synchronous, no barriers ----
    const int npan = (kk + 7) >> 3;
    for (int p = 0; p < npan; ++p) {
        const int rem = kk - 8 * p;
        const int jmax = (rem + 7) >> 3;         // live slots (1..8), uniform

        #pragma unroll
        for (int tt = 0; tt < 8; ++tt) {
            if (tt < rem) {
                const int t = 8 * p + tt;
                double dp  = __shfl(T[0][0], 9 * tt);   // diag owner lane
                double rzt = __shfl(rz[0], tt);          // lane tt, lc=0
                double inv = 1.0 / dp;
                if (lane == t) dsave = dp;
                q_acc = fma(rzt * inv, rzt, q_acc);      // q += rzt^2/d

                double ar[8], cc[8];
                #pragma unroll
                for (int j = 0; j < 8; ++j)
                    ar[j] = (j < jmax)
                          ? __shfl(T[j][0], 8 * tt + lr) * inv : 0.0;
                #pragma unroll
                for (int m = 0; m < 8; ++m)
                    cc[m] = (m < jmax)
                          ? __shfl(T[m][0], 8 * tt + lc) : 0.0;

                #pragma unroll
                for (int j = 0; j < 8; ++j) {
                    if (j < jmax) {
                        #pragma unroll
                        for (int m = 0; m < 8; ++m)
                            if (m < jmax)
                                T[j][m] = fma(-ar[j], cc[m], T[j][m]);
                        rz[j] = fma(-ar[j], rzt, rz[j]);
                    }
                }
            }
        }
        // ---- double panel shift: rows AND cols down one slot (static) ----
        #pragma unroll
        for (int j = 0; j < 7; ++j) {
            #pragma unroll
            for (int m = 0; m < 7; ++m)
                T[j][m] = T[j + 1][m + 1];
            rz[j] = rz[j + 1];
        }
    }

    // ---- logdet: one log per lane; q_acc already identical in all lanes ----
    double ld = log(dsave);
    for (int off = 32; off; off >>= 1)
        ld += __shfl_down(ld, off);
    if (lane == 0)
        out[b] = (float)(0.5 * (q_acc + ld + (double)kk * LOG_2PI));
}

// ---------------------------------------------------------------------------
// Kernel 2b: fallback, fixed 128-block grid driven by the straggler list.
// 256 threads: 2 threads per row splitting the column range (R14-verified).
// ---------------------------------------------------------------------------
__global__ __launch_bounds__(256) void nll_kernel_big(
    const float* __restrict__ x,
    const int*   __restrict__ mask,
    const float* __restrict__ mu,
    const double* __restrict__ cov,
    float* __restrict__ out,
    const int* __restrict__ bigcount,
    const int* __restrict__ biglist)
{
    __shared__ double S[NPACK];    // 40400 B
    __shared__ double col[DD];
    __shared__ double rz[DD];
    __shared__ int obs[DD];
    __shared__ int kk_sh;
    __shared__ double pq[4], pl[4];

    int nbig = *bigcount;
    if (nbig > BIGCAP) nbig = BIGCAP;
    if (blockIdx.x >= nbig) return;
    const int b = biglist[blockIdx.x];

    const int tid = threadIdx.x;
    const int lane = tid & 63;
    const int wv = tid >> 6;

    if (wv == 0) {
        int i1 = lane + 64;
        int m0 = (mask[b * DD + lane] != 0);
        int m1 = (i1 < DD) ? (mask[b * DD + i1] != 0) : 0;
        unsigned long long b0 = __ballot(m0);
        unsigned long long bb1 = __ballot(m1);
        unsigned long long lowmask = (1ull << lane) - 1ull;
        int k0 = __popcll(b0);
        if (m0) obs[__popcll(b0 & lowmask)] = lane;
        if (m1) obs[k0 + __popcll(bb1 & lowmask)] = i1;
        if (lane == 0) kk_sh = k0 + __popcll(bb1);
    }
    __syncthreads();
    const int kk = kk_sh;

    if (tid < kk) {
        int g = obs[tid];
        rz[tid] = (double)(x[b * DD + g] - mu[g]);
    }

    int T = kk * (kk + 1) / 2;
    for (int t = tid; t < T; t += 256) {
        int i = (int)((sqrt(8.0 * (double)t + 1.0) - 1.0) * 0.5);
        while ((i + 1) * (i + 2) / 2 <= t) ++i;
        while (i * (i + 1) / 2 > t) --i;
        int j = t - i * (i + 1) / 2;
        double val = cov[obs[i] * DD + obs[j]];
        if (i == j) val += JITTER;
        S[t] = val;
    }
    __syncthreads();

    for (int p = 0; p < kk; ++p) {
        if (tid < kk - p) {
            int l = p + tid;
            col[l] = S[l * (l + 1) / 2 + p];
        }
        __syncthreads();
        double inv = 1.0 / col[p];
        double rzp = rz[p];
        int r = tid >> 1, half = tid & 1;
        int i = p + 1 + r;
        if (i < kk) {
            double* Srow = S + i * (i + 1) / 2;
            double ai = col[i] * inv;
            int lo = p + 1;
            int len = i - p;                 // cols p+1..i inclusive
            int mid = lo + (len >> 1);
            int from = half ? mid : lo;
            int to   = half ? (i + 1) : mid;
            #pragma unroll 4
            for (int l2 = from; l2 < to; ++l2)
                Srow[l2] -= ai * col[l2];
            if (half == 0) rz[i] -= ai * rzp;
        }
        __syncthreads();
    }

    double q = 0.0, ld = 0.0;
    if (tid < kk) {
        double dj = S[tid * (tid + 1) / 2 + tid];
        ld = log(dj);
        double zj = rz[tid];
        q = zj * zj / dj;
    }
    for (int off = 32; off; off >>= 1) {
        q  += __shfl_down(q, off);
        ld += __shfl_down(ld, off);
    }
    if (lane == 0) { pq[wv] = q; pl[wv] = ld; }
    __syncthreads();
    if (tid == 0)
        out[b] = (float)(0.5 * (pq[0] + pq[1] + pq[2] + pq[3]
                                + pl[0] + pl[1] + pl[2] + pl[3]
                                + (double)kk * LOG_2PI));
}

// ---------------------------------------------------------------------------
extern "C" void kernel_launch(void* const* d_in, const int* in_sizes, int n_in,
                              void* d_out, int out_size, void* d_ws, size_t ws_size,
                              hipStream_t stream)
{
    const float* x         = (const float*)d_in[0];
    const int*   mask      = (const int*)d_in[1];
    const float* mu        = (const float*)d_in[2];
    const float* log_diag  = (const float*)d_in[3];
    const float* lower_tri = (const float*)d_in[4];
    float* out = (float*)d_out;

    double* cov    = (double*)d_ws;                       // 80000 B
    int* bigcount  = (int*)((char*)d_ws + 80000);         // 4 B
    int* biglist   = (int*)((char*)d_ws + 80000 + 128);   // BIGCAP*4 B

    const int Bn = in_sizes[0] / DD;

    hipMemsetAsync(bigcount, 0, sizeof(int), stream);
    build_cov_kernel<<<(DD * DD + 255) / 256, 256, 0, stream>>>(log_diag, lower_tri, cov);
    nll_kernel_tile<<<(Bn + WPB - 1) / WPB, 256, 0, stream>>>(
        x, mask, mu, cov, out, bigcount, biglist, Bn);
    nll_kernel_big<<<128, 256, 0, stream>>>(x, mask, mu, cov, out, bigcount, biglist);
}

// Round 17
// 232.927 us; speedup vs baseline: 2.0489x; 1.0188x over previous
//
#include <hip/hip_runtime.h>
#include <math.h>

#define DD 100
#define NTRIL 4950                 // D*(D-1)/2
#define NPACK (DD * (DD + 1) / 2)  // 5050
#define LOG_2PI 1.8378770664093453
#define JITTER 5.5e-8              // calibrated vs np twin (R7-R9 probes)
#define RCAP 64                    // tier-1 register tile capacity
#define R2CAP 72                   // tier-2 9-slot register tile capacity
#define WPB 4                      // waves (samples) per block in tier 1
#define BIGCAP 256                 // straggler list capacity

// ---------------------------------------------------------------------------
// Kernel 1: cov = A * A^T in fp64 (exact).
// ---------------------------------------------------------------------------
__global__ __launch_bounds__(256) void build_cov_kernel(
    const float* __restrict__ log_diag,
    const float* __restrict__ lower_tri,
    double* __restrict__ cov)
{
    __shared__ double sLow[NTRIL];
    __shared__ double sDiag[DD];
    for (int t = threadIdx.x; t < NTRIL; t += blockDim.x)
        sLow[t] = (double)lower_tri[t];
    for (int t = threadIdx.x; t < DD; t += blockDim.x)
        sDiag[t] = exp((double)log_diag[t]);
    __syncthreads();

    int idx = blockIdx.x * blockDim.x + threadIdx.x;
    if (idx >= DD * DD) return;
    int i = idx / DD;
    int j = idx % DD;
    int mn = (i < j) ? i : j;
    int bi = i * (i - 1) / 2;
    int bj = j * (j - 1) / 2;
    double acc = 0.0;
    for (int t = 0; t < mn; ++t)
        acc += sLow[bi + t] * sLow[bj + t];
    double ai = (mn < i) ? sLow[bi + mn] : sDiag[i];
    double aj = (mn < j) ? sLow[bj + mn] : sDiag[j];
    cov[idx] = acc + ai * aj;
}

// ---------------------------------------------------------------------------
// Kernel 2a (tier 1): 2D register-tiled LDL^T, kk <= 64. Four samples/block.
// UNCHANGED from R16 (110 us, verified). kk > 64 -> list A.
// ---------------------------------------------------------------------------
__global__ __launch_bounds__(256, 2) void nll_kernel_tile(
    const float* __restrict__ x,
    const int*   __restrict__ mask,
    const float* __restrict__ mu,
    const double* __restrict__ cov,
    float* __restrict__ out,
    int* __restrict__ bigcount,
    int* __restrict__ biglist,
    int Bn)
{
    __shared__ int obs[WPB][RCAP];

    const int wid  = threadIdx.x >> 6;
    const int lane = threadIdx.x & 63;
    const int b = blockIdx.x * WPB + wid;
    if (b >= Bn) return;

    const int lr = lane & 7;
    const int lc = lane >> 3;

    int i1 = lane + 64;
    int m0 = (mask[b * DD + lane] != 0);
    int m1v = (i1 < DD) ? (mask[b * DD + i1] != 0) : 0;
    unsigned long long b0 = __ballot(m0);
    unsigned long long bb1 = __ballot(m1v);
    unsigned long long lowmask = (1ull << lane) - 1ull;
    int k0 = __popcll(b0);
    int pos0 = __popcll(b0 & lowmask);
    int pos1 = k0 + __popcll(bb1 & lowmask);
    const int kk = k0 + __popcll(bb1);
    if (m0 && pos0 < RCAP) obs[wid][pos0] = lane;
    if (m1v && pos1 < RCAP) obs[wid][pos1] = i1;
    if (lane >= kk && lane < RCAP) obs[wid][lane] = 0;
    __syncthreads();
    if (kk > RCAP) {                   // straggler: enqueue to list A, bail
        if (lane == 0) {
            int idx = atomicAdd(bigcount, 1);
            if (idx < BIGCAP) biglist[idx] = b;
        }
        return;
    }

    int rows[8], cols[8];
    #pragma unroll
    for (int j = 0; j < 8; ++j) rows[j] = obs[wid][8 * j + lr];
    #pragma unroll
    for (int m = 0; m < 8; ++m) cols[m] = obs[wid][8 * m + lc];

    double T[8][8];
    #pragma unroll
    for (int j = 0; j < 8; ++j) {
        const int gr = 8 * j + lr;
        #pragma unroll
        for (int m = 0; m < 8; ++m) {
            const int gc = 8 * m + lc;
            double v = 0.0;
            if (gr < kk && gc <= gr) {
                v = cov[rows[j] * DD + cols[m]];
                if (gr == gc) v += JITTER;
            }
            T[j][m] = v;
        }
    }

    double rz[8];
    #pragma unroll
    for (int j = 0; j < 8; ++j) {
        const int gr = 8 * j + lr;
        double v = 0.0;
        if (gr < kk) {
            int g = rows[j];
            v = (double)(x[b * DD + g] - mu[g]);
        }
        rz[j] = v;
    }

    double q_acc = 0.0;
    double dsave = 1.0;

    const int npan = (kk + 7) >> 3;
    for (int p = 0; p < npan; ++p) {
        const int rem = kk - 8 * p;
        const int jmax = (rem + 7) >> 3;

        #pragma unroll
        for (int tt = 0; tt < 8; ++tt) {
            if (tt < rem) {
                const int t = 8 * p + tt;
                double dp  = __shfl(T[0][0], 9 * tt);
                double rzt = __shfl(rz[0], tt);
                double inv = 1.0 / dp;
                if (lane == t) dsave = dp;
                q_acc = fma(rzt * inv, rzt, q_acc);

                double ar[8], cc[8];
                #pragma unroll
                for (int j = 0; j < 8; ++j)
                    ar[j] = (j < jmax)
                          ? __shfl(T[j][0], 8 * tt + lr) * inv : 0.0;
                #pragma unroll
                for (int m = 0; m < 8; ++m)
                    cc[m] = (m < jmax)
                          ? __shfl(T[m][0], 8 * tt + lc) : 0.0;

                #pragma unroll
                for (int j = 0; j < 8; ++j) {
                    if (j < jmax) {
                        #pragma unroll
                        for (int m = 0; m < 8; ++m)
                            if (m < jmax)
                                T[j][m] = fma(-ar[j], cc[m], T[j][m]);
                        rz[j] = fma(-ar[j], rzt, rz[j]);
                    }
                }
            }
        }
        #pragma unroll
        for (int j = 0; j < 7; ++j) {
            #pragma unroll
            for (int m = 0; m < 7; ++m)
                T[j][m] = T[j + 1][m + 1];
            rz[j] = rz[j + 1];
        }
    }

    double ld = log(dsave);
    for (int off = 32; off; off >>= 1)
        ld += __shfl_down(ld, off);
    if (lane == 0)
        out[b] = (float)(0.5 * (q_acc + ld + (double)kk * LOG_2PI));
}

// ---------------------------------------------------------------------------
// Kernel 2b (tier 2): 9-slot register-tiled LDL^T for 64 < kk <= 72.
// One wave per block, launch_bounds(64,1) -> VGPR cap 512: the 81-double
// tile (~235 regs) cannot spill. Same wave-synchronous algorithm as tier 1
// (stride-8 slot maps; diag owner lane 9*tt; two dsave regs since pivot
// index can exceed 63). Consumes list A; kk > 72 forwarded to list B.
// ---------------------------------------------------------------------------
__global__ __launch_bounds__(64, 1) void nll_kernel_reg9(
    const float* __restrict__ x,
    const int*   __restrict__ mask,
    const float* __restrict__ mu,
    const double* __restrict__ cov,
    float* __restrict__ out,
    const int* __restrict__ bigcount,
    const int* __restrict__ biglist,
    int* __restrict__ big2count,
    int* __restrict__ big2list)
{
    __shared__ int obs[R2CAP];

    int nbig = *bigcount;
    if (nbig > BIGCAP) nbig = BIGCAP;
    if ((int)blockIdx.x >= nbig) return;
    const int b = biglist[blockIdx.x];

    const int lane = threadIdx.x;
    const int lr = lane & 7;
    const int lc = lane >> 3;

    int i1 = lane + 64;
    int m0 = (mask[b * DD + lane] != 0);
    int m1v = (i1 < DD) ? (mask[b * DD + i1] != 0) : 0;
    unsigned long long b0 = __ballot(m0);
    unsigned long long bb1 = __ballot(m1v);
    unsigned long long lowmask = (1ull << lane) - 1ull;
    int k0 = __popcll(b0);
    int pos0 = __popcll(b0 & lowmask);
    int pos1 = k0 + __popcll(bb1 & lowmask);
    const int kk = k0 + __popcll(bb1);
    if (m0 && pos0 < R2CAP) obs[pos0] = lane;
    if (m1v && pos1 < R2CAP) obs[pos1] = i1;
    if (lane >= kk - 8 && lane + 8 < R2CAP) obs[lane + 8] = obs[lane + 8]; // no-op placeholder
    __syncthreads();
    if (kk > R2CAP) {                  // forward to tier 3
        if (lane == 0) {
            int idx = atomicAdd(big2count, 1);
            if (idx < BIGCAP) big2list[idx] = b;
        }
        return;
    }
    // park unused slots (obs indices in [kk, 72))
    if (lane == 0)
        for (int t = kk; t < R2CAP; ++t) obs[t] = 0;
    __syncthreads();

    int rows[9], cols[9];
    #pragma unroll
    for (int j = 0; j < 9; ++j) rows[j] = obs[8 * j + lr];
    #pragma unroll
    for (int m = 0; m < 9; ++m) cols[m] = obs[8 * m + lc];

    double T[9][9];
    #pragma unroll
    for (int j = 0; j < 9; ++j) {
        const int gr = 8 * j + lr;
        #pragma unroll
        for (int m = 0; m < 9; ++m) {
            const int gc = 8 * m + lc;
            double v = 0.0;
            if (gr < kk && gc <= gr) {
                v = cov[rows[j] * DD + cols[m]];
                if (gr == gc) v += JITTER;
            }
            T[j][m] = v;
        }
    }

    double rz[9];
    #pragma unroll
    for (int j = 0; j < 9; ++j) {
        const int gr = 8 * j + lr;
        double v = 0.0;
        if (gr < kk) {
            int g = rows[j];
            v = (double)(x[b * DD + g] - mu[g]);
        }
        rz[j] = v;
    }

    double q_acc = 0.0;
    double dsave = 1.0, dsave2 = 1.0;   // lane L: pivots L and L+64

    const int npan = (kk + 7) >> 3;     // up to 9
    for (int p = 0; p < npan; ++p) {
        const int rem = kk - 8 * p;
        const int jmax = (rem + 7) >> 3;  // 1..9

        #pragma unroll
        for (int tt = 0; tt < 8; ++tt) {
            if (tt < rem) {
                const int t = 8 * p + tt;
                double dp  = __shfl(T[0][0], 9 * tt);
                double rzt = __shfl(rz[0], tt);
                double inv = 1.0 / dp;
                if (lane == t) dsave = dp;
                if (lane + 64 == t) dsave2 = dp;
                q_acc = fma(rzt * inv, rzt, q_acc);

                double ar[9], cc[9];
                #pragma unroll
                for (int j = 0; j < 9; ++j)
                    ar[j] = (j < jmax)
                          ? __shfl(T[j][0], 8 * tt + lr) * inv : 0.0;
                #pragma unroll
                for (int m = 0; m < 9; ++m)
                    cc[m] = (m < jmax)
                          ? __shfl(T[m][0], 8 * tt + lc) : 0.0;

                #pragma unroll
                for (int j = 0; j < 9; ++j) {
                    if (j < jmax) {
                        #pragma unroll
                        for (int m = 0; m < 9; ++m)
                            if (m < jmax)
                                T[j][m] = fma(-ar[j], cc[m], T[j][m]);
                        rz[j] = fma(-ar[j], rzt, rz[j]);
                    }
                }
            }
        }
        #pragma unroll
        for (int j = 0; j < 8; ++j) {
            #pragma unroll
            for (int m = 0; m < 8; ++m)
                T[j][m] = T[j + 1][m + 1];
            rz[j] = rz[j + 1];
        }
    }

    double ld = log(dsave) + log(dsave2);
    for (int off = 32; off; off >>= 1)
        ld += __shfl_down(ld, off);
    if (lane == 0)
        out[b] = (float)(0.5 * (q_acc + ld + (double)kk * LOG_2PI));
}

// ---------------------------------------------------------------------------
// Kernel 2c (tier 3): staged-LDS solve for kk > 72 (list B; ~never runs).
// R16-verified structure, 256 threads.
// ---------------------------------------------------------------------------
__global__ __launch_bounds__(256) void nll_kernel_big(
    const float* __restrict__ x,
    const int*   __restrict__ mask,
    const float* __restrict__ mu,
    const double* __restrict__ cov,
    float* __restrict__ out,
    const int* __restrict__ big2count,
    const int* __restrict__ big2list)
{
    __shared__ double S[NPACK];
    __shared__ double col[DD];
    __shared__ double rz[DD];
    __shared__ int obs[DD];
    __shared__ int kk_sh;
    __shared__ double pq[4], pl[4];

    int nbig = *big2count;
    if (nbig > BIGCAP) nbig = BIGCAP;
    if ((int)blockIdx.x >= nbig) return;
    const int b = big2list[blockIdx.x];

    const int tid = threadIdx.x;
    const int lane = tid & 63;
    const int wv = tid >> 6;

    if (wv == 0) {
        int i1 = lane + 64;
        int m0 = (mask[b * DD + lane] != 0);
        int m1 = (i1 < DD) ? (mask[b * DD + i1] != 0) : 0;
        unsigned long long b0 = __ballot(m0);
        unsigned long long bb1 = __ballot(m1);
        unsigned long long lowmask = (1ull << lane) - 1ull;
        int k0 = __popcll(b0);
        if (m0) obs[__popcll(b0 & lowmask)] = lane;
        if (m1) obs[k0 + __popcll(bb1 & lowmask)] = i1;
        if (lane == 0) kk_sh = k0 + __popcll(bb1);
    }
    __syncthreads();
    const int kk = kk_sh;

    if (tid < kk) {
        int g = obs[tid];
        rz[tid] = (double)(x[b * DD + g] - mu[g]);
    }

    int T = kk * (kk + 1) / 2;
    for (int t = tid; t < T; t += 256) {
        int i = (int)((sqrt(8.0 * (double)t + 1.0) - 1.0) * 0.5);
        while ((i + 1) * (i + 2) / 2 <= t) ++i;
        while (i * (i + 1) / 2 > t) --i;
        int j = t - i * (i + 1) / 2;
        double val = cov[obs[i] * DD + obs[j]];
        if (i == j) val += JITTER;
        S[t] = val;
    }
    __syncthreads();

    for (int p = 0; p < kk; ++p) {
        if (tid < kk - p) {
            int l = p + tid;
            col[l] = S[l * (l + 1) / 2 + p];
        }
        __syncthreads();
        double inv = 1.0 / col[p];
        double rzp = rz[p];
        int r = tid >> 1, half = tid & 1;
        int i = p + 1 + r;
        if (i < kk) {
            double* Srow = S + i * (i + 1) / 2;
            double ai = col[i] * inv;
            int lo = p + 1;
            int len = i - p;
            int mid = lo + (len >> 1);
            int from = half ? mid : lo;
            int to   = half ? (i + 1) : mid;
            #pragma unroll 4
            for (int l2 = from; l2 < to; ++l2)
                Srow[l2] -= ai * col[l2];
            if (half == 0) rz[i] -= ai * rzp;
        }
        __syncthreads();
    }

    double q = 0.0, ld = 0.0;
    if (tid < kk) {
        double dj = S[tid * (tid + 1) / 2 + tid];
        ld = log(dj);
        double zj = rz[tid];
        q = zj * zj / dj;
    }
    for (int off = 32; off; off >>= 1) {
        q  += __shfl_down(q, off);
        ld += __shfl_down(ld, off);
    }
    if (lane == 0) { pq[wv] = q; pl[wv] = ld; }
    __syncthreads();
    if (tid == 0)
        out[b] = (float)(0.5 * (pq[0] + pq[1] + pq[2] + pq[3]
                                + pl[0] + pl[1] + pl[2] + pl[3]
                                + (double)kk * LOG_2PI));
}

// ---------------------------------------------------------------------------
extern "C" void kernel_launch(void* const* d_in, const int* in_sizes, int n_in,
                              void* d_out, int out_size, void* d_ws, size_t ws_size,
                              hipStream_t stream)
{
    const float* x         = (const float*)d_in[0];
    const int*   mask      = (const int*)d_in[1];
    const float* mu        = (const float*)d_in[2];
    const float* log_diag  = (const float*)d_in[3];
    const float* lower_tri = (const float*)d_in[4];
    float* out = (float*)d_out;

    double* cov    = (double*)d_ws;                            // 80000 B
    int* bigcount  = (int*)((char*)d_ws + 80000);              // 4 B
    int* big2count = (int*)((char*)d_ws + 80004);              // 4 B
    int* biglist   = (int*)((char*)d_ws + 80128);              // BIGCAP*4
    int* big2list  = (int*)((char*)d_ws + 80128 + 4 * BIGCAP); // BIGCAP*4

    const int Bn = in_sizes[0] / DD;

    hipMemsetAsync(bigcount, 0, 8, stream);   // zero both counters
    build_cov_kernel<<<(DD * DD + 255) / 256, 256, 0, stream>>>(log_diag, lower_tri, cov);
    nll_kernel_tile<<<(Bn + WPB - 1) / WPB, 256, 0, stream>>>(
        x, mask, mu, cov, out, bigcount, biglist, Bn);
    nll_kernel_reg9<<<BIGCAP, 64, 0, stream>>>(
        x, mask, mu, cov, out, bigcount, biglist, big2count, big2list);
    nll_kernel_big<<<16, 256, 0, stream>>>(x, mask, mu, cov, out, big2count, big2list);
}

// Round 18
// 200.764 us; speedup vs baseline: 2.3771x; 1.1602x over previous
//
#include <hip/hip_runtime.h>
#include <math.h>

#define DD 100
#define NTRIL 4950                 // D*(D-1)/2
#define NPACK (DD * (DD + 1) / 2)  // 5050
#define LOG_2PI 1.8378770664093453
#define JITTER 5.5e-8              // calibrated vs np twin (R7-R9 probes)
#define RCAP 64                    // tier-1 register tile capacity
#define R2CAP 72                   // tier-2 9-slot register tile capacity
#define WPB 4                      // waves (samples) per block in tier 1
#define BIGCAP 256                 // straggler list capacity (ws layout)

// ---------------------------------------------------------------------------
// Kernel 1: cov = A * A^T in fp64 (exact). Also zeroes the straggler
// counters (replaces the hipMemsetAsync dispatch).
// ---------------------------------------------------------------------------
__global__ __launch_bounds__(256) void build_cov_kernel(
    const float* __restrict__ log_diag,
    const float* __restrict__ lower_tri,
    double* __restrict__ cov,
    int* __restrict__ counters)
{
    if (blockIdx.x == 0 && threadIdx.x == 0) {
        counters[0] = 0;
        counters[1] = 0;
    }
    __shared__ double sLow[NTRIL];
    __shared__ double sDiag[DD];
    for (int t = threadIdx.x; t < NTRIL; t += blockDim.x)
        sLow[t] = (double)lower_tri[t];
    for (int t = threadIdx.x; t < DD; t += blockDim.x)
        sDiag[t] = exp((double)log_diag[t]);
    __syncthreads();

    int idx = blockIdx.x * blockDim.x + threadIdx.x;
    if (idx >= DD * DD) return;
    int i = idx / DD;
    int j = idx % DD;
    int mn = (i < j) ? i : j;
    int bi = i * (i - 1) / 2;
    int bj = j * (j - 1) / 2;
    double acc = 0.0;
    for (int t = 0; t < mn; ++t)
        acc += sLow[bi + t] * sLow[bj + t];
    double ai = (mn < i) ? sLow[bi + mn] : sDiag[i];
    double aj = (mn < j) ? sLow[bj + mn] : sDiag[j];
    cov[idx] = acc + ai * aj;
}

// ---------------------------------------------------------------------------
// Kernel 2a (tier 1): 2D register-tiled LDL^T, kk <= 64. Four samples/block.
// Register diet vs R17: ar[8] array removed (a_j computed inline per row,
// same fma order -> bit-identical). __launch_bounds__(256,3): 170-reg cap
// -> 3 waves/SIMD (was 2 at ~204 regs). kk > 64 -> list A.
// ---------------------------------------------------------------------------
__global__ __launch_bounds__(256, 3) void nll_kernel_tile(
    const float* __restrict__ x,
    const int*   __restrict__ mask,
    const float* __restrict__ mu,
    const double* __restrict__ cov,
    float* __restrict__ out,
    int* __restrict__ bigcount,
    int* __restrict__ biglist,
    int Bn)
{
    __shared__ int obs[WPB][RCAP];

    const int wid  = threadIdx.x >> 6;
    const int lane = threadIdx.x & 63;
    const int b = blockIdx.x * WPB + wid;
    if (b >= Bn) return;

    const int lr = lane & 7;
    const int lc = lane >> 3;

    int i1 = lane + 64;
    int m0 = (mask[b * DD + lane] != 0);
    int m1v = (i1 < DD) ? (mask[b * DD + i1] != 0) : 0;
    unsigned long long b0 = __ballot(m0);
    unsigned long long bb1 = __ballot(m1v);
    unsigned long long lowmask = (1ull << lane) - 1ull;
    int k0 = __popcll(b0);
    int pos0 = __popcll(b0 & lowmask);
    int pos1 = k0 + __popcll(bb1 & lowmask);
    const int kk = k0 + __popcll(bb1);
    if (m0 && pos0 < RCAP) obs[wid][pos0] = lane;
    if (m1v && pos1 < RCAP) obs[wid][pos1] = i1;
    if (lane >= kk && lane < RCAP) obs[wid][lane] = 0;
    __syncthreads();
    if (kk > RCAP) {                   // straggler: enqueue to list A, bail
        if (lane == 0) {
            int idx = atomicAdd(bigcount, 1);
            if (idx < BIGCAP) biglist[idx] = b;
        }
        return;
    }

    int rows[8], cols[8];
    #pragma unroll
    for (int j = 0; j < 8; ++j) rows[j] = obs[wid][8 * j + lr];
    #pragma unroll
    for (int m = 0; m < 8; ++m) cols[m] = obs[wid][8 * m + lc];

    double T[8][8];
    #pragma unroll
    for (int j = 0; j < 8; ++j) {
        const int gr = 8 * j + lr;
        #pragma unroll
        for (int m = 0; m < 8; ++m) {
            const int gc = 8 * m + lc;
            double v = 0.0;
            if (gr < kk && gc <= gr) {
                v = cov[rows[j] * DD + cols[m]];
                if (gr == gc) v += JITTER;
            }
            T[j][m] = v;
        }
    }

    double rz[8];
    #pragma unroll
    for (int j = 0; j < 8; ++j) {
        const int gr = 8 * j + lr;
        double v = 0.0;
        if (gr < kk) {
            int g = rows[j];
            v = (double)(x[b * DD + g] - mu[g]);
        }
        rz[j] = v;
    }

    double q_acc = 0.0;
    double dsave = 1.0;

    const int npan = (kk + 7) >> 3;
    for (int p = 0; p < npan; ++p) {
        const int rem = kk - 8 * p;
        const int jmax = (rem + 7) >> 3;

        #pragma unroll
        for (int tt = 0; tt < 8; ++tt) {
            if (tt < rem) {
                const int t = 8 * p + tt;
                double dp  = __shfl(T[0][0], 9 * tt);
                double rzt = __shfl(rz[0], tt);
                double inv = 1.0 / dp;
                if (lane == t) dsave = dp;
                q_acc = fma(rzt * inv, rzt, q_acc);

                double cc[8];
                #pragma unroll
                for (int m = 0; m < 8; ++m)
                    cc[m] = (m < jmax)
                          ? __shfl(T[m][0], 8 * tt + lc) : 0.0;

                #pragma unroll
                for (int j = 0; j < 8; ++j) {
                    if (j < jmax) {
                        double aj = __shfl(T[j][0], 8 * tt + lr) * inv;
                        #pragma unroll
                        for (int m = 0; m < 8; ++m)
                            if (m < jmax)
                                T[j][m] = fma(-aj, cc[m], T[j][m]);
                        rz[j] = fma(-aj, rzt, rz[j]);
                    }
                }
            }
        }
        #pragma unroll
        for (int j = 0; j < 7; ++j) {
            #pragma unroll
            for (int m = 0; m < 7; ++m)
                T[j][m] = T[j + 1][m + 1];
            rz[j] = rz[j + 1];
        }
    }

    double ld = log(dsave);
    for (int off = 32; off; off >>= 1)
        ld += __shfl_down(ld, off);
    if (lane == 0)
        out[b] = (float)(0.5 * (q_acc + ld + (double)kk * LOG_2PI));
}

// ---------------------------------------------------------------------------
// Kernel 2b (tier 2): 9-slot register-tiled LDL^T for 64 < kk <= 72.
// One wave per block, launch_bounds(64,1) -> no spill risk (~235 regs).
// Consumes list A; kk > 72 forwarded to list B.
// ---------------------------------------------------------------------------
__global__ __launch_bounds__(64, 1) void nll_kernel_reg9(
    const float* __restrict__ x,
    const int*   __restrict__ mask,
    const float* __restrict__ mu,
    const double* __restrict__ cov,
    float* __restrict__ out,
    const int* __restrict__ bigcount,
    const int* __restrict__ biglist,
    int* __restrict__ big2count,
    int* __restrict__ big2list)
{
    __shared__ int obs[R2CAP];

    int nbig = *bigcount;
    if (nbig > BIGCAP) nbig = BIGCAP;
    if ((int)blockIdx.x >= nbig) return;
    const int b = biglist[blockIdx.x];

    const int lane = threadIdx.x;
    const int lr = lane & 7;
    const int lc = lane >> 3;

    int i1 = lane + 64;
    int m0 = (mask[b * DD + lane] != 0);
    int m1v = (i1 < DD) ? (mask[b * DD + i1] != 0) : 0;
    unsigned long long b0 = __ballot(m0);
    unsigned long long bb1 = __ballot(m1v);
    unsigned long long lowmask = (1ull << lane) - 1ull;
    int k0 = __popcll(b0);
    int pos0 = __popcll(b0 & lowmask);
    int pos1 = k0 + __popcll(bb1 & lowmask);
    const int kk = k0 + __popcll(bb1);
    if (m0 && pos0 < R2CAP) obs[pos0] = lane;
    if (m1v && pos1 < R2CAP) obs[pos1] = i1;
    __syncthreads();
    if (kk > R2CAP) {                  // forward to tier 3
        if (lane == 0) {
            int idx = atomicAdd(big2count, 1);
            if (idx < BIGCAP) big2list[idx] = b;
        }
        return;
    }
    if (lane == 0)
        for (int t = kk; t < R2CAP; ++t) obs[t] = 0;
    __syncthreads();

    int rows[9], cols[9];
    #pragma unroll
    for (int j = 0; j < 9; ++j) rows[j] = obs[8 * j + lr];
    #pragma unroll
    for (int m = 0; m < 9; ++m) cols[m] = obs[8 * m + lc];

    double T[9][9];
    #pragma unroll
    for (int j = 0; j < 9; ++j) {
        const int gr = 8 * j + lr;
        #pragma unroll
        for (int m = 0; m < 9; ++m) {
            const int gc = 8 * m + lc;
            double v = 0.0;
            if (gr < kk && gc <= gr) {
                v = cov[rows[j] * DD + cols[m]];
                if (gr == gc) v += JITTER;
            }
            T[j][m] = v;
        }
    }

    double rz[9];
    #pragma unroll
    for (int j = 0; j < 9; ++j) {
        const int gr = 8 * j + lr;
        double v = 0.0;
        if (gr < kk) {
            int g = rows[j];
            v = (double)(x[b * DD + g] - mu[g]);
        }
        rz[j] = v;
    }

    double q_acc = 0.0;
    double dsave = 1.0, dsave2 = 1.0;

    const int npan = (kk + 7) >> 3;
    for (int p = 0; p < npan; ++p) {
        const int rem = kk - 8 * p;
        const int jmax = (rem + 7) >> 3;

        #pragma unroll
        for (int tt = 0; tt < 8; ++tt) {
            if (tt < rem) {
                const int t = 8 * p + tt;
                double dp  = __shfl(T[0][0], 9 * tt);
                double rzt = __shfl(rz[0], tt);
                double inv = 1.0 / dp;
                if (lane == t) dsave = dp;
                if (lane + 64 == t) dsave2 = dp;
                q_acc = fma(rzt * inv, rzt, q_acc);

                double cc[9];
                #pragma unroll
                for (int m = 0; m < 9; ++m)
                    cc[m] = (m < jmax)
                          ? __shfl(T[m][0], 8 * tt + lc) : 0.0;

                #pragma unroll
                for (int j = 0; j < 9; ++j) {
                    if (j < jmax) {
                        double aj = __shfl(T[j][0], 8 * tt + lr) * inv;
                        #pragma unroll
                        for (int m = 0; m < 9; ++m)
                            if (m < jmax)
                                T[j][m] = fma(-aj, cc[m], T[j][m]);
                        rz[j] = fma(-aj, rzt, rz[j]);
                    }
                }
            }
        }
        #pragma unroll
        for (int j = 0; j < 8; ++j) {
            #pragma unroll
            for (int m = 0; m < 8; ++m)
                T[j][m] = T[j + 1][m + 1];
            rz[j] = rz[j + 1];
        }
    }

    double ld = log(dsave) + log(dsave2);
    for (int off = 32; off; off >>= 1)
        ld += __shfl_down(ld, off);
    if (lane == 0)
        out[b] = (float)(0.5 * (q_acc + ld + (double)kk * LOG_2PI));
}

// ---------------------------------------------------------------------------
// Kernel 2c (tier 3): staged-LDS solve for kk > 72 (list B; ~never runs).
// ---------------------------------------------------------------------------
__global__ __launch_bounds__(256) void nll_kernel_big(
    const float* __restrict__ x,
    const int*   __restrict__ mask,
    const float* __restrict__ mu,
    const double* __restrict__ cov,
    float* __restrict__ out,
    const int* __restrict__ big2count,
    const int* __restrict__ big2list)
{
    __shared__ double S[NPACK];
    __shared__ double col[DD];
    __shared__ double rz[DD];
    __shared__ int obs[DD];
    __shared__ int kk_sh;
    __shared__ double pq[4], pl[4];

    int nbig = *big2count;
    if (nbig > BIGCAP) nbig = BIGCAP;
    if ((int)blockIdx.x >= nbig) return;
    const int b = big2list[blockIdx.x];

    const int tid = threadIdx.x;
    const int lane = tid & 63;
    const int wv = tid >> 6;

    if (wv == 0) {
        int i1 = lane + 64;
        int m0 = (mask[b * DD + lane] != 0);
        int m1 = (i1 < DD) ? (mask[b * DD + i1] != 0) : 0;
        unsigned long long b0 = __ballot(m0);
        unsigned long long bb1 = __ballot(m1);
        unsigned long long lowmask = (1ull << lane) - 1ull;
        int k0 = __popcll(b0);
        if (m0) obs[__popcll(b0 & lowmask)] = lane;
        if (m1) obs[k0 + __popcll(bb1 & lowmask)] = i1;
        if (lane == 0) kk_sh = k0 + __popcll(bb1);
    }
    __syncthreads();
    const int kk = kk_sh;

    if (tid < kk) {
        int g = obs[tid];
        rz[tid] = (double)(x[b * DD + g] - mu[g]);
    }

    int T = kk * (kk + 1) / 2;
    for (int t = tid; t < T; t += 256) {
        int i = (int)((sqrt(8.0 * (double)t + 1.0) - 1.0) * 0.5);
        while ((i + 1) * (i + 2) / 2 <= t) ++i;
        while (i * (i + 1) / 2 > t) --i;
        int j = t - i * (i + 1) / 2;
        double val = cov[obs[i] * DD + obs[j]];
        if (i == j) val += JITTER;
        S[t] = val;
    }
    __syncthreads();

    for (int p = 0; p < kk; ++p) {
        if (tid < kk - p) {
            int l = p + tid;
            col[l] = S[l * (l + 1) / 2 + p];
        }
        __syncthreads();
        double inv = 1.0 / col[p];
        double rzp = rz[p];
        int r = tid >> 1, half = tid & 1;
        int i = p + 1 + r;
        if (i < kk) {
            double* Srow = S + i * (i + 1) / 2;
            double ai = col[i] * inv;
            int lo = p + 1;
            int len = i - p;
            int mid = lo + (len >> 1);
            int from = half ? mid : lo;
            int to   = half ? (i + 1) : mid;
            #pragma unroll 4
            for (int l2 = from; l2 < to; ++l2)
                Srow[l2] -= ai * col[l2];
            if (half == 0) rz[i] -= ai * rzp;
        }
        __syncthreads();
    }

    double q = 0.0, ld = 0.0;
    if (tid < kk) {
        double dj = S[tid * (tid + 1) / 2 + tid];
        ld = log(dj);
        double zj = rz[tid];
        q = zj * zj / dj;
    }
    for (int off = 32; off; off >>= 1) {
        q  += __shfl_down(q, off);
        ld += __shfl_down(ld, off);
    }
    if (lane == 0) { pq[wv] = q; pl[wv] = ld; }
    __syncthreads();
    if (tid == 0)
        out[b] = (float)(0.5 * (pq[0] + pq[1] + pq[2] + pq[3]
                                + pl[0] + pl[1] + pl[2] + pl[3]
                                + (double)kk * LOG_2PI));
}

// ---------------------------------------------------------------------------
extern "C" void kernel_launch(void* const* d_in, const int* in_sizes, int n_in,
                              void* d_out, int out_size, void* d_ws, size_t ws_size,
                              hipStream_t stream)
{
    const float* x         = (const float*)d_in[0];
    const int*   mask      = (const int*)d_in[1];
    const float* mu        = (const float*)d_in[2];
    const float* log_diag  = (const float*)d_in[3];
    const float* lower_tri = (const float*)d_in[4];
    float* out = (float*)d_out;

    double* cov    = (double*)d_ws;                            // 80000 B
    int* counters  = (int*)((char*)d_ws + 80000);              // 8 B
    int* biglist   = (int*)((char*)d_ws + 80128);              // BIGCAP*4
    int* big2list  = (int*)((char*)d_ws + 80128 + 4 * BIGCAP); // BIGCAP*4

    const int Bn = in_sizes[0] / DD;

    build_cov_kernel<<<(DD * DD + 255) / 256, 256, 0, stream>>>(
        log_diag, lower_tri, cov, counters);
    nll_kernel_tile<<<(Bn + WPB - 1) / WPB, 256, 0, stream>>>(
        x, mask, mu, cov, out, counters, biglist, Bn);
    nll_kernel_reg9<<<32, 64, 0, stream>>>(
        x, mask, mu, cov, out, counters, biglist, counters + 1, big2list);
    nll_kernel_big<<<8, 256, 0, stream>>>(x, mask, mu, cov, out, counters + 1, big2list);
}

// Round 20
// 198.012 us; speedup vs baseline: 2.4101x; 1.0139x over previous
//
#include <hip/hip_runtime.h>
#include <math.h>

#define DD 100
#define NTRIL 4950                 // D*(D-1)/2
#define NPACK (DD * (DD + 1) / 2)  // 5050
#define LOG_2PI 1.8378770664093453
#define JITTER 5.5e-8              // calibrated vs np twin (R7-R9 probes)
#define RCAP 64                    // tier-1 register tile capacity
#define R2CAP 72                   // straggler 9-slot register tile capacity
#define WPB 4                      // waves (samples) per block in tier 1
#define BIGCAP 256                 // straggler list capacity (ws layout)

// ---------------------------------------------------------------------------
// Kernel 1: cov = A * A^T in fp64 (exact). Zeroes the straggler counter.
// ---------------------------------------------------------------------------
__global__ __launch_bounds__(256) void build_cov_kernel(
    const float* __restrict__ log_diag,
    const float* __restrict__ lower_tri,
    double* __restrict__ cov,
    int* __restrict__ counters)
{
    if (blockIdx.x == 0 && threadIdx.x == 0)
        counters[0] = 0;
    __shared__ double sLow[NTRIL];
    __shared__ double sDiag[DD];
    for (int t = threadIdx.x; t < NTRIL; t += blockDim.x)
        sLow[t] = (double)lower_tri[t];
    for (int t = threadIdx.x; t < DD; t += blockDim.x)
        sDiag[t] = exp((double)log_diag[t]);
    __syncthreads();

    int idx = blockIdx.x * blockDim.x + threadIdx.x;
    if (idx >= DD * DD) return;
    int i = idx / DD;
    int j = idx % DD;
    int mn = (i < j) ? i : j;
    int bi = i * (i - 1) / 2;
    int bj = j * (j - 1) / 2;
    double acc = 0.0;
    for (int t = 0; t < mn; ++t)
        acc += sLow[bi + t] * sLow[bj + t];
    double ai = (mn < i) ? sLow[bi + mn] : sDiag[i];
    double aj = (mn < j) ? sLow[bj + mn] : sDiag[j];
    cov[idx] = acc + ai * aj;
}

// ---------------------------------------------------------------------------
// Kernel 2a (tier 1): EXACT R18-verified shfl register-tile LDL^T, kk <= 64.
// Four samples/block. NOTE (R19 lesson): same-wave cross-lane LDS without a
// barrier is a C++ data race the compiler WILL break — __shfl is the only
// barrier-free broadcast. kk > 64 -> straggler list.
// ---------------------------------------------------------------------------
__global__ __launch_bounds__(256, 3) void nll_kernel_tile(
    const float* __restrict__ x,
    const int*   __restrict__ mask,
    const float* __restrict__ mu,
    const double* __restrict__ cov,
    float* __restrict__ out,
    int* __restrict__ bigcount,
    int* __restrict__ biglist,
    int Bn)
{
    __shared__ int obs[WPB][RCAP];

    const int wid  = threadIdx.x >> 6;
    const int lane = threadIdx.x & 63;
    const int b = blockIdx.x * WPB + wid;
    if (b >= Bn) return;

    const int lr = lane & 7;
    const int lc = lane >> 3;

    int i1 = lane + 64;
    int m0 = (mask[b * DD + lane] != 0);
    int m1v = (i1 < DD) ? (mask[b * DD + i1] != 0) : 0;
    unsigned long long b0 = __ballot(m0);
    unsigned long long bb1 = __ballot(m1v);
    unsigned long long lowmask = (1ull << lane) - 1ull;
    int k0 = __popcll(b0);
    int pos0 = __popcll(b0 & lowmask);
    int pos1 = k0 + __popcll(bb1 & lowmask);
    const int kk = k0 + __popcll(bb1);
    if (m0 && pos0 < RCAP) obs[wid][pos0] = lane;
    if (m1v && pos1 < RCAP) obs[wid][pos1] = i1;
    if (lane >= kk && lane < RCAP) obs[wid][lane] = 0;
    __syncthreads();
    if (kk > RCAP) {                   // straggler: enqueue, bail (wave-uniform)
        if (lane == 0) {
            int idx = atomicAdd(bigcount, 1);
            if (idx < BIGCAP) biglist[idx] = b;
        }
        return;
    }

    int rows[8], cols[8];
    #pragma unroll
    for (int j = 0; j < 8; ++j) rows[j] = obs[wid][8 * j + lr];
    #pragma unroll
    for (int m = 0; m < 8; ++m) cols[m] = obs[wid][8 * m + lc];

    double T[8][8];
    #pragma unroll
    for (int j = 0; j < 8; ++j) {
        const int gr = 8 * j + lr;
        #pragma unroll
        for (int m = 0; m < 8; ++m) {
            const int gc = 8 * m + lc;
            double v = 0.0;
            if (gr < kk && gc <= gr) {
                v = cov[rows[j] * DD + cols[m]];
                if (gr == gc) v += JITTER;
            }
            T[j][m] = v;
        }
    }

    double rz[8];
    #pragma unroll
    for (int j = 0; j < 8; ++j) {
        const int gr = 8 * j + lr;
        double v = 0.0;
        if (gr < kk) {
            int g = rows[j];
            v = (double)(x[b * DD + g] - mu[g]);
        }
        rz[j] = v;
    }

    double q_acc = 0.0;
    double dsave = 1.0;

    const int npan = (kk + 7) >> 3;
    for (int p = 0; p < npan; ++p) {
        const int rem = kk - 8 * p;
        const int jmax = (rem + 7) >> 3;

        #pragma unroll
        for (int tt = 0; tt < 8; ++tt) {
            if (tt < rem) {
                const int t = 8 * p + tt;
                double dp  = __shfl(T[0][0], 9 * tt);
                double rzt = __shfl(rz[0], tt);
                double inv = 1.0 / dp;
                if (lane == t) dsave = dp;
                q_acc = fma(rzt * inv, rzt, q_acc);

                double cc[8];
                #pragma unroll
                for (int m = 0; m < 8; ++m)
                    cc[m] = (m < jmax)
                          ? __shfl(T[m][0], 8 * tt + lc) : 0.0;

                #pragma unroll
                for (int j = 0; j < 8; ++j) {
                    if (j < jmax) {
                        double aj = __shfl(T[j][0], 8 * tt + lr) * inv;
                        #pragma unroll
                        for (int m = 0; m < 8; ++m)
                            if (m < jmax)
                                T[j][m] = fma(-aj, cc[m], T[j][m]);
                        rz[j] = fma(-aj, rzt, rz[j]);
                    }
                }
            }
        }
        #pragma unroll
        for (int j = 0; j < 7; ++j) {
            #pragma unroll
            for (int m = 0; m < 7; ++m)
                T[j][m] = T[j + 1][m + 1];
            rz[j] = rz[j + 1];
        }
    }

    double ld = log(dsave);
    for (int off = 32; off; off >>= 1)
        ld += __shfl_down(ld, off);
    if (lane == 0)
        out[b] = (float)(0.5 * (q_acc + ld + (double)kk * LOG_2PI));
}

// ---------------------------------------------------------------------------
// Kernel 2b: merged straggler kernel (single dispatch). One wave per block.
// kk <= 72: 9-slot shfl register tile (logic identical to verified R17/R18
// reg9). kk > 72 (never observed): staged-LDS safety net.
// ---------------------------------------------------------------------------
__global__ __launch_bounds__(64, 1) void nll_kernel_straggler(
    const float* __restrict__ x,
    const int*   __restrict__ mask,
    const float* __restrict__ mu,
    const double* __restrict__ cov,
    float* __restrict__ out,
    const int* __restrict__ bigcount,
    const int* __restrict__ biglist)
{
    __shared__ int obs[DD];
    __shared__ double S[NPACK];     // used only on the kk>72 path
    __shared__ double colS[DD];
    __shared__ double rzS[DD];

    int nbig = *bigcount;
    if (nbig > BIGCAP) nbig = BIGCAP;
    if ((int)blockIdx.x >= nbig) return;
    const int b = biglist[blockIdx.x];

    const int lane = threadIdx.x;
    const int lr = lane & 7;
    const int lc = lane >> 3;

    int i1 = lane + 64;
    int m0 = (mask[b * DD + lane] != 0);
    int m1v = (i1 < DD) ? (mask[b * DD + i1] != 0) : 0;
    unsigned long long b0 = __ballot(m0);
    unsigned long long bb1 = __ballot(m1v);
    unsigned long long lowmask = (1ull << lane) - 1ull;
    int k0 = __popcll(b0);
    int pos0 = __popcll(b0 & lowmask);
    int pos1 = k0 + __popcll(bb1 & lowmask);
    const int kk = k0 + __popcll(bb1);
    if (m0) obs[pos0] = lane;
    if (m1v) obs[pos1] = i1;
    __syncthreads();

    if (kk <= R2CAP) {
        // ---------------- 9-slot register path (verified R17/R18) ----------
        if (lane == 0)
            for (int t = kk; t < R2CAP; ++t) obs[t] = 0;
        __syncthreads();

        int rows[9], cols[9];
        #pragma unroll
        for (int j = 0; j < 9; ++j) rows[j] = obs[8 * j + lr];
        #pragma unroll
        for (int m = 0; m < 9; ++m) cols[m] = obs[8 * m + lc];

        double T[9][9];
        #pragma unroll
        for (int j = 0; j < 9; ++j) {
            const int gr = 8 * j + lr;
            #pragma unroll
            for (int m = 0; m < 9; ++m) {
                const int gc = 8 * m + lc;
                double v = 0.0;
                if (gr < kk && gc <= gr) {
                    v = cov[rows[j] * DD + cols[m]];
                    if (gr == gc) v += JITTER;
                }
                T[j][m] = v;
            }
        }

        double rz[9];
        #pragma unroll
        for (int j = 0; j < 9; ++j) {
            const int gr = 8 * j + lr;
            double v = 0.0;
            if (gr < kk) {
                int g = rows[j];
                v = (double)(x[b * DD + g] - mu[g]);
            }
            rz[j] = v;
        }

        double q_acc = 0.0;
        double dsave = 1.0, dsave2 = 1.0;

        const int npan = (kk + 7) >> 3;
        for (int p = 0; p < npan; ++p) {
            const int rem = kk - 8 * p;
            const int jmax = (rem + 7) >> 3;

            #pragma unroll
            for (int tt = 0; tt < 8; ++tt) {
                if (tt < rem) {
                    const int t = 8 * p + tt;
                    double dp  = __shfl(T[0][0], 9 * tt);
                    double rzt = __shfl(rz[0], tt);
                    double inv = 1.0 / dp;
                    if (lane == t) dsave = dp;
                    if (lane + 64 == t) dsave2 = dp;
                    q_acc = fma(rzt * inv, rzt, q_acc);

                    double cc[9];
                    #pragma unroll
                    for (int m = 0; m < 9; ++m)
                        cc[m] = (m < jmax)
                              ? __shfl(T[m][0], 8 * tt + lc) : 0.0;

                    #pragma unroll
                    for (int j = 0; j < 9; ++j) {
                        if (j < jmax) {
                            double aj = __shfl(T[j][0], 8 * tt + lr) * inv;
                            #pragma unroll
                            for (int m = 0; m < 9; ++m)
                                if (m < jmax)
                                    T[j][m] = fma(-aj, cc[m], T[j][m]);
                            rz[j] = fma(-aj, rzt, rz[j]);
                        }
                    }
                }
            }
            #pragma unroll
            for (int j = 0; j < 8; ++j) {
                #pragma unroll
                for (int m = 0; m < 8; ++m)
                    T[j][m] = T[j + 1][m + 1];
                rz[j] = rz[j + 1];
            }
        }

        double ld = log(dsave) + log(dsave2);
        for (int off = 32; off; off >>= 1)
            ld += __shfl_down(ld, off);
        if (lane == 0)
            out[b] = (float)(0.5 * (q_acc + ld + (double)kk * LOG_2PI));
        return;
    }

    // ---------------- kk > 72: staged-LDS path (safety net) ----------------
    for (int i = lane; i < kk; i += 64) {
        int g = obs[i];
        rzS[i] = (double)(x[b * DD + g] - mu[g]);
    }
    int T2 = kk * (kk + 1) / 2;
    for (int t = lane; t < T2; t += 64) {
        int i = (int)((sqrt(8.0 * (double)t + 1.0) - 1.0) * 0.5);
        while ((i + 1) * (i + 2) / 2 <= t) ++i;
        while (i * (i + 1) / 2 > t) --i;
        int j = t - i * (i + 1) / 2;
        double val = cov[obs[i] * DD + obs[j]];
        if (i == j) val += JITTER;
        S[t] = val;
    }
    __syncthreads();

    for (int p = 0; p < kk; ++p) {
        for (int l = p + lane; l < kk; l += 64)
            colS[l] = S[l * (l + 1) / 2 + p];
        __syncthreads();
        double inv = 1.0 / colS[p];
        double rzp = rzS[p];
        for (int i = p + 1 + lane; i < kk; i += 64) {
            double* Srow = S + i * (i + 1) / 2;
            double ai = colS[i] * inv;
            #pragma unroll 4
            for (int l = p + 1; l <= i; ++l)
                Srow[l] -= ai * colS[l];
            rzS[i] -= ai * rzp;
        }
        __syncthreads();
    }

    double q = 0.0, ld = 0.0;
    for (int j = lane; j < kk; j += 64) {
        double dj = S[j * (j + 1) / 2 + j];
        ld += log(dj);
        double zj = rzS[j];
        q += zj * zj / dj;
    }
    for (int off = 32; off; off >>= 1) {
        q  += __shfl_down(q, off);
        ld += __shfl_down(ld, off);
    }
    if (lane == 0)
        out[b] = (float)(0.5 * (q + ld + (double)kk * LOG_2PI));
}

// ---------------------------------------------------------------------------
extern "C" void kernel_launch(void* const* d_in, const int* in_sizes, int n_in,
                              void* d_out, int out_size, void* d_ws, size_t ws_size,
                              hipStream_t stream)
{
    const float* x         = (const float*)d_in[0];
    const int*   mask      = (const int*)d_in[1];
    const float* mu        = (const float*)d_in[2];
    const float* log_diag  = (const float*)d_in[3];
    const float* lower_tri = (const float*)d_in[4];
    float* out = (float*)d_out;

    double* cov    = (double*)d_ws;                            // 80000 B
    int* counters  = (int*)((char*)d_ws + 80000);              // 4 B
    int* biglist   = (int*)((char*)d_ws + 80128);              // BIGCAP*4

    const int Bn = in_sizes[0] / DD;

    build_cov_kernel<<<(DD * DD + 255) / 256, 256, 0, stream>>>(
        log_diag, lower_tri, cov, counters);
    nll_kernel_tile<<<(Bn + WPB - 1) / WPB, 256, 0, stream>>>(
        x, mask, mu, cov, out, counters, biglist, Bn);
    nll_kernel_straggler<<<32, 64, 0, stream>>>(
        x, mask, mu, cov, out, counters, biglist);
}